// Round 11
// baseline (62.512 us; speedup 1.0000x reference)
//
#include <hip/hip_runtime.h>
#include <cstdint>

// out[b,o] = max_k min(m[b,k], clamp(w[k,o],0,1)); B=1024, IN=512, OUT=256, fp32.
// Round 11: leaner exact early-exit.
//   - wave-parallel prefix scan for bucket offsets (was serial tid==0 loop)
//   - phase 1: positions 0..31 straight-line, NO barriers -> 32 loads in flight
//     (exit before 32 terms is probabilistically impossible on this data, and
//      skipping the vote only costs work, never correctness)
//   - phase 2: vote-then-process every 8 via __syncthreads_and (1 barrier, no LDS)
// Exact fp32 math; worst case = full 512-walk (bounded).

constexpr int IN  = 512;
constexpr int OUT = 256;

static __device__ __forceinline__ float clamp01(float x) {
  return fminf(fmaxf(x, 0.0f), 1.0f);      // v_med3_f32
}

__global__ __launch_bounds__(256, 4)
void minmax_topk(const float* __restrict__ m, const float* __restrict__ w,
                 float* __restrict__ out) {
  __shared__ int   cnt[32];
  __shared__ int   start[32];
  __shared__ int   ord[IN];      // position -> k index (bucket-descending)
  __shared__ float mv[IN];       // position -> m value

  const int tid = threadIdx.x;
  const int b   = blockIdx.x;
  const float* mrow = m + (size_t)b * IN;

  if (tid < 32) cnt[tid] = 0;
  __syncthreads();

  // Each thread owns elements tid and tid+256.
  const float v0 = mrow[tid];
  const float v1 = mrow[tid + 256];
  const int q0 = min((int)(v0 * 32.0f), 31);
  const int q1 = min((int)(v1 * 32.0f), 31);
  atomicAdd(&cnt[q0], 1);
  atomicAdd(&cnt[q1], 1);
  __syncthreads();

  // Descending-bucket exclusive prefix (lane d covers bucket q = 31-d),
  // wave-parallel shfl_up scan -- replaces the serial 32-iteration loop.
  if (tid < 32) {
    const int q = 31 - tid;
    const int x = cnt[q];
    int incl = x;
#pragma unroll
    for (int o = 1; o < 32; o <<= 1) {
      int t = __shfl_up(incl, o, 32);
      if (tid >= o) incl += t;
    }
    start[q] = incl - x;         // exclusive offset in descending order
  }
  __syncthreads();

  {                              // scatter (within-bucket order arbitrary)
    int p0 = atomicAdd(&start[q0], 1); ord[p0] = tid;       mv[p0] = v0;
    int p1 = atomicAdd(&start[q1], 1); ord[p1] = tid + 256; mv[p1] = v1;
  }
  __syncthreads();

  float acc = 0.0f;              // min(m,wc) >= 0, so 0 is a safe identity

#define CHUNK8(P)                                                         \
  {                                                                       \
    const float cm0 = mv[(P) + 0]; const int ci0 = ord[(P) + 0];          \
    const float cm1 = mv[(P) + 1]; const int ci1 = ord[(P) + 1];          \
    const float cm2 = mv[(P) + 2]; const int ci2 = ord[(P) + 2];          \
    const float cm3 = mv[(P) + 3]; const int ci3 = ord[(P) + 3];          \
    const float cm4 = mv[(P) + 4]; const int ci4 = ord[(P) + 4];          \
    const float cm5 = mv[(P) + 5]; const int ci5 = ord[(P) + 5];          \
    const float cm6 = mv[(P) + 6]; const int ci6 = ord[(P) + 6];          \
    const float cm7 = mv[(P) + 7]; const int ci7 = ord[(P) + 7];          \
    const float cw0 = w[(size_t)ci0 * OUT + tid];                         \
    const float cw1 = w[(size_t)ci1 * OUT + tid];                         \
    const float cw2 = w[(size_t)ci2 * OUT + tid];                         \
    const float cw3 = w[(size_t)ci3 * OUT + tid];                         \
    const float cw4 = w[(size_t)ci4 * OUT + tid];                         \
    const float cw5 = w[(size_t)ci5 * OUT + tid];                         \
    const float cw6 = w[(size_t)ci6 * OUT + tid];                         \
    const float cw7 = w[(size_t)ci7 * OUT + tid];                         \
    acc = fmaxf(acc, fminf(cm0, clamp01(cw0)));                           \
    acc = fmaxf(acc, fminf(cm1, clamp01(cw1)));                           \
    acc = fmaxf(acc, fminf(cm2, clamp01(cw2)));                           \
    acc = fmaxf(acc, fminf(cm3, clamp01(cw3)));                           \
    acc = fmaxf(acc, fminf(cm4, clamp01(cw4)));                           \
    acc = fmaxf(acc, fminf(cm5, clamp01(cw5)));                           \
    acc = fmaxf(acc, fminf(cm6, clamp01(cw6)));                           \
    acc = fmaxf(acc, fminf(cm7, clamp01(cw7)));                           \
  }

  // Phase 1: top 32 positions, no votes, no barriers -> full load overlap.
  CHUNK8(0)
  CHUNK8(8)
  CHUNK8(16)
  CHUNK8(24)

  // Phase 2: vote-then-process every 8 terms.
  for (int p = 32; p < IN; p += 8) {
    const int   qn    = min((int)(mv[p] * 32.0f), 31);
    const float bound = (float)(qn + 1) * 0.03125f;   // ceiling of next bucket
    if (__syncthreads_and(acc >= bound)) break;       // all remaining terms <= acc
    CHUNK8(p)
  }
#undef CHUNK8

  out[(size_t)b * OUT + tid] = acc;
}

extern "C" void kernel_launch(void* const* d_in, const int* in_sizes, int n_in,
                              void* d_out, int out_size, void* d_ws, size_t ws_size,
                              hipStream_t stream) {
  (void)n_in; (void)out_size; (void)d_ws; (void)ws_size;
  const float* m = (const float*)d_in[0];
  const float* w = (const float*)d_in[1];
  float* out = (float*)d_out;
  const int B = in_sizes[0] / IN;           // 1024 blocks, one row each
  minmax_topk<<<dim3(B), 256, 0, stream>>>(m, w, out);
}